// Round 14
// baseline (694.433 us; speedup 1.0000x reference)
//
#include <hip/hip_runtime.h>
#include <hip/hip_bf16.h>
#include <math.h>

#define NB 16
#define SS 1024
#define DD 512
#define HD 256

typedef unsigned short US;
typedef short bf16x8 __attribute__((ext_vector_type(8)));
typedef float f32x4 __attribute__((ext_vector_type(4)));
typedef __attribute__((address_space(1))) const void gv1;
typedef __attribute__((address_space(3))) void lv3;

static __device__ __forceinline__ float b2sf(US u){ return __uint_as_float(((unsigned)u)<<16); }
static __device__ __forceinline__ US f2b(float f){
  __hip_bfloat16 h = __float2bfloat16(f);
  union { __hip_bfloat16 h; US u; } c; c.h = h; return c.u;
}
static __device__ __forceinline__ float rd(const void* __restrict__ p, long i, int isf){
  return isf ? ((const float*)p)[i] : b2sf(((const US*)p)[i]);
}

__global__ void k_detect(const void* __restrict__ x, int* __restrict__ flag){
  const US* u = (const US*)x;
  int t = threadIdx.x;
  float m = 0.f;
  for (int i = t; i < 4096; i += 256){
    float v = fabsf(b2sf(u[i]));
    if (isnan(v) || isinf(v)) v = 1e30f;
    m = fmaxf(m, v);
  }
  for (int off = 32; off; off >>= 1) m = fmaxf(m, __shfl_down(m, off));
  __shared__ float sh[4];
  if ((t & 63) == 0) sh[t >> 6] = m;
  __syncthreads();
  if (t == 0){
    float mm = fmaxf(fmaxf(sh[0], sh[1]), fmaxf(sh[2], sh[3]));
    flag[0] = (mm > 1e6f) ? 1 : 0;
  }
}

struct WTab { const void* src[8]; long start[9]; int type[8]; int C[8]; };
__global__ void k_prep_w(WTab wt, US* __restrict__ dst, const int* __restrict__ fl){
  int isf = fl[0];
  long i = (long)blockIdx.x*256 + threadIdx.x;
  if (i >= wt.start[8]) return;
  int s = 0;
  while (i >= wt.start[s+1]) s++;
  long r = i - wt.start[s];
  long si;
  if (wt.type[s] == 0){
    int C = wt.C[s]; long oc3 = 3L*C;
    int o = (int)(r / oc3); int rr = (int)(r - (long)o*oc3); int t = rr / C; int c = rr - t*C;
    si = ((long)o*C + c)*3 + t;
  } else if (wt.type[s] == 1){
    int k = (int)(r >> 18); int e = (int)((r >> 9) & 511); int d = (int)(r & 511);
    si = ((long)(k*512 + d))*512 + e;
  } else si = r;
  dst[i] = f2b(rd(wt.src[s], si, isf));
}

struct FTab { const void* src[14]; int start[15]; };
__global__ void k_cvt_all(FTab ft, float* __restrict__ dst, const int* __restrict__ fl){
  int isf = fl[0];
  int i = blockIdx.x*256 + threadIdx.x;
  if (i >= ft.start[14]) return;
  int s = 0;
  while (i >= ft.start[s+1]) s++;
  dst[i] = rd(ft.src[s], i - ft.start[s], isf);
}

__global__ void k_build_g(float* __restrict__ g){
  int d = blockIdx.x*256 + threadIdx.x;
  if (d >= SS) return;
  float s = 1.f;
  for (int k = 1; k < 102; ++k){
    int r = (k*d) & (SS-1);
    s += 2.f * cosf(6.28318530718f * (float)r * (1.f/SS));
  }
  g[d] = s * (1.f/SS);
}
__global__ void k_build_cmat(const float* __restrict__ g, US* __restrict__ cm){
  int i = blockIdx.x*256 + threadIdx.x;
  if (i >= SS*SS) return;
  int t = i >> 10, s = i & (SS-1);
  cm[i] = f2b(g[(s - t) & (SS-1)]);
}
__global__ __launch_bounds__(256) void k_transpose_b(const void* __restrict__ x, US* __restrict__ xt, const int* __restrict__ fl){
  int isf = fl[0];
  __shared__ float tl[32][33];
  int b = blockIdx.z, s0 = blockIdx.x*32, d0 = blockIdx.y*32;
  int tx = threadIdx.x & 31, ty = threadIdx.x >> 5;
  for (int i = ty; i < 32; i += 8)
    tl[i][tx] = rd(x, ((long)(b*SS + s0+i))*DD + d0+tx, isf);
  __syncthreads();
  for (int i = ty; i < 32; i += 8)
    xt[((long)(b*DD + d0+i))*SS + s0+tx] = f2b(tl[tx][i]);
}

// ---------------- 128x128 register-pipelined MFMA GEMM (k_pipe) ----------------
// 4 waves (2m x 2n), wave out 64x64. 3-slot ring: A slot s at s*4096 US (8 KiB),
// B slot s at 12288 + s*4096. 48 KiB -> 3 blocks/CU at launch_bounds(256,3).
// Body t: ds_read slice t+1 -> nxt regs; stage slice t+3; MFMA(cur) hides LDS latency;
// lgkmcnt(0)+sched_barrier; vmcnt(4) (slice t+2 confirmed); ONE barrier per slice.
template<int EPI, bool TAPPED>
__global__ __launch_bounds__(256, 3) void k_pipe(
    const US* __restrict__ A, const US* __restrict__ Bact, void* __restrict__ Out,
    int NYB, int K, long sBbytes, int ldbB, int dil,
    long sOut, int ldo, const float* __restrict__ bias)
{
  __shared__ alignas(16) US ring[24576];   // 48 KiB
  const int bx = blockIdx.x;
  const int ny = bx % NYB, b = bx / NYB;
  const int m0 = blockIdx.y*128, n0 = ny*128;
  const int dd = (TAPPED && dil < 0) ? (1 << (m0 >> 9)) : dil;
  const char* Bb = (const char*)Bact + (long)b*sBbytes;
  const int tid = threadIdx.x;
  const int lane = tid & 63, w = tid >> 6;   // 4 waves
  const int wm = w >> 1, wn = w & 1;
  const int col = lane & 15, g = lane >> 4;
  const int NTs = K >> 5;

  int offA[4], offB[4];
  #pragma unroll
  for (int mf = 0; mf < 4; mf++){
    int r = wm*64 + mf*16 + col;
    int wg = ((r & 1) << 2) | g;
    offA[mf] = (r >> 1)*128 + ((wg ^ ((r >> 1) & 7)) << 4);
  }
  #pragma unroll
  for (int nf = 0; nf < 4; nf++){
    int r = wn*64 + nf*16 + col;
    int wg = ((r & 1) << 2) | g;
    offB[nf] = (r >> 1)*128 + ((wg ^ ((r >> 1) & 7)) << 4);
  }
  int rl[2], gg[2];
  #pragma unroll
  for (int j = 0; j < 2; j++){
    int c = w*128 + j*64 + lane;
    int R = c >> 3, f = c & 7;
    int wg = f ^ (R & 7);
    rl[j] = 2*R + (wg >> 2);
    gg[j] = wg & 3;
  }

  auto stageA = [&](int t){
    int slot = t % 3, kb = t << 5;
    #pragma unroll
    for (int j = 0; j < 2; j++){
      const char* ga = (const char*)A + ((long)(m0 + rl[j])*K + kb + gg[j]*8)*2;
      __builtin_amdgcn_global_load_lds((gv1*)ga, (lv3*)&ring[slot*4096 + w*1024 + j*512], 16, 0, 0);
    }
  };
  auto stageB = [&](int t){
    int slot = t % 3, kb = t << 5;
    int c0 = TAPPED ? (kb & 511) : kb;
    int tapoff = TAPPED ? (((kb >> 9) - 1)*dd) : 0;
    #pragma unroll
    for (int j = 0; j < 2; j++){
      int brow = n0 + rl[j] + tapoff;
      if (TAPPED) brow = brow < 0 ? 0 : (brow > SS-1 ? SS-1 : brow);
      const char* gb = Bb + (long)brow*ldbB + (c0 + gg[j]*8)*2;
      __builtin_amdgcn_global_load_lds((gv1*)gb, (lv3*)&ring[12288 + slot*4096 + w*1024 + j*512], 16, 0, 0);
    }
  };

  f32x4 acc[4][4];
  #pragma unroll
  for (int i = 0; i < 4; i++)
    #pragma unroll
    for (int j = 0; j < 4; j++) acc[i][j] = (f32x4){0.f,0.f,0.f,0.f};

  // prologue: slices 0,1,2 in flight (4 ops each per thread = 12)
  stageA(0); stageB(0);
  stageA(1); stageB(1);
  stageA(2); stageB(2);
  asm volatile("s_waitcnt vmcnt(4)" ::: "memory");   // slices 0,1 landed
  __builtin_amdgcn_s_barrier();

  bf16x8 a0[4], b0[4], a1[4], b1[4];
  {
    const char* As_ = (const char*)&ring[0];
    const char* Bs_ = (const char*)&ring[12288];
    #pragma unroll
    for (int f = 0; f < 4; f++){ a0[f] = *(const bf16x8*)(As_ + offA[f]); b0[f] = *(const bf16x8*)(Bs_ + offB[f]); }
    asm volatile("s_waitcnt lgkmcnt(0)" ::: "memory");
    __builtin_amdgcn_sched_barrier(0);
  }

#define PIPE_BODY(cA, cB, nA, nB, t)                                             \
  {                                                                              \
    if ((t) + 1 < NTs){                                                          \
      int sl = ((t) + 1) % 3;                                                    \
      const char* As_ = (const char*)&ring[sl*4096];                             \
      const char* Bs_ = (const char*)&ring[12288 + sl*4096];                     \
      nA[0] = *(const bf16x8*)(As_ + offA[0]);                                   \
      nA[1] = *(const bf16x8*)(As_ + offA[1]);                                   \
      nA[2] = *(const bf16x8*)(As_ + offA[2]);                                   \
      nA[3] = *(const bf16x8*)(As_ + offA[3]);                                   \
      nB[0] = *(const bf16x8*)(Bs_ + offB[0]);                                   \
      nB[1] = *(const bf16x8*)(Bs_ + offB[1]);                                   \
      nB[2] = *(const bf16x8*)(Bs_ + offB[2]);                                   \
      nB[3] = *(const bf16x8*)(Bs_ + offB[3]);                                   \
    }                                                                            \
    if ((t) + 3 < NTs){ stageA((t) + 3); stageB((t) + 3); }                      \
    __builtin_amdgcn_s_setprio(1);                                               \
    _Pragma("unroll")                                                            \
    for (int mf = 0; mf < 4; mf++)                                               \
      _Pragma("unroll")                                                          \
      for (int nf = 0; nf < 4; nf++)                                             \
        acc[mf][nf] = __builtin_amdgcn_mfma_f32_16x16x32_bf16(cA[mf], cB[nf], acc[mf][nf], 0, 0, 0); \
    __builtin_amdgcn_s_setprio(0);                                               \
    asm volatile("s_waitcnt lgkmcnt(0)" ::: "memory");                           \
    __builtin_amdgcn_sched_barrier(0);                                           \
    if ((t) < NTs - 3) asm volatile("s_waitcnt vmcnt(4)" ::: "memory");          \
    else               asm volatile("s_waitcnt vmcnt(0)" ::: "memory");          \
    __builtin_amdgcn_s_barrier();                                                \
  }

  for (int ks = 0; ks < NTs; ks += 2){
    PIPE_BODY(a0, b0, a1, b1, ks);
    PIPE_BODY(a1, b1, a0, b0, ks + 1);
  }
#undef PIPE_BODY

  // ---- epilogue: acc -> swizzled 32 KiB LDS tile -> coalesced stores ----
  US* tile = ring;
  #pragma unroll
  for (int mf = 0; mf < 4; mf++){
    int m_l = wm*64 + mf*16 + g*4;
    float4 bb = *(const float4*)&bias[m0 + m_l];
    const float* bp = (const float*)&bb;
    #pragma unroll
    for (int nf = 0; nf < 4; nf++){
      int n_l = wn*64 + nf*16 + col;
      f32x4 v = acc[mf][nf];
      US pk[4];
      #pragma unroll
      for (int r = 0; r < 4; r++){
        float val = v[r] + bp[r];
        if (EPI == 1) val = 0.5f*val*(1.f + erff(val*0.70710678f));
        pk[r] = f2b(val);
      }
      int byte = n_l*256 + ((m_l*2) ^ ((n_l & 7) << 4));
      *(int2*)((char*)tile + byte) = *(int2*)pk;
    }
  }
  __syncthreads();
  const int r0 = tid >> 4, c = tid & 15;
  #pragma unroll
  for (int p = 0; p < 8; p++){
    int r = p*16 + r0;
    int4 vv = *(const int4*)((const char*)tile + r*256 + ((c*16) ^ ((r & 7) << 4)));
    *(int4*)((US*)Out + (long)b*sOut + (long)(n0 + r)*ldo + m0 + c*8) = vv;
  }
}

// ---------------- 128x128 MFMA GEMM ----------------
// EPI: 0=bias store out[b][n][m]; 2=+bn+silu; 3=+silu; 4=wavelet-fused;
//      5=NT store out[b][m][n]; 6=bias store + aux1=x-val + aux2=silu(val).
template<int EPI, bool TAPPED>
__global__ __launch_bounds__(256) void k_mfma(
    const US* __restrict__ A, const US* __restrict__ Bact, void* __restrict__ Out,
    int NYB, int K, long sBbytes, int ldbB, int dil,
    long sOut, int ldo,
    const float* __restrict__ bias, const float* __restrict__ s1v, const float* __restrict__ s2v,
    const float* __restrict__ psiP, const void* __restrict__ xres,
    US* __restrict__ aux1, US* __restrict__ aux2, const int* __restrict__ fl)
{
  __shared__ alignas(16) US shb[2*128*64];
  __shared__ float psh[(EPI==4) ? 512 : 4];
  US* As = shb;
  US* Bs = shb + 128*64;
  const int bx = blockIdx.x;
  const int ny = bx % NYB;
  const int b  = bx / NYB;
  const int m00 = blockIdx.y*128, n0 = ny*128;
  const int dd = (TAPPED && dil < 0) ? (1 << (m00 >> 9)) : dil;
  const char* Bb = (const char*)Bact + (long)b*sBbytes;
  const int tid = threadIdx.x;
  const int lane = tid & 63, w = tid >> 6;
  const int wr = w >> 1, wc = w & 1;
  const int col = lane & 15, g = lane >> 4;

  if (EPI == 4){
    for (int i = tid; i < 512; i += 256)
      psh[i] = psiP[(long)b*4096 + (i >> 7)*SS + n0 + (i & 127)];
  }

  f32x4 acc[4][4];
  f32x4 facc[4][4];
  if (EPI == 4){
    #pragma unroll
    for (int i = 0; i < 4; i++)
      #pragma unroll
      for (int j = 0; j < 4; j++) facc[i][j] = (f32x4){0.f,0.f,0.f,0.f};
  }

  int rows_[4], sls_[4];
  #pragma unroll
  for (int i = 0; i < 4; i++){
    int c = w*256 + i*64 + lane;
    rows_[i] = c >> 3;
    sls_[i] = (c & 7) ^ ((c >> 3) & 7);
  }

  const int NKC = (EPI == 4) ? 4 : 1;
  for (int kc = 0; kc < NKC; ++kc){
    #pragma unroll
    for (int i = 0; i < 4; i++)
      #pragma unroll
      for (int j = 0; j < 4; j++) acc[i][j] = (f32x4){0.f,0.f,0.f,0.f};

    for (int k0 = 0; k0 < K; k0 += 64){
      const int c0 = TAPPED ? (k0 & 511) : k0;
      const int tapoff = TAPPED ? (((k0 >> 9) - 1)*dd) : 0;
      __syncthreads();
      #pragma unroll
      for (int i = 0; i < 4; i++){
        const long arow = (long)(m00 + rows_[i]) + (EPI==4 ? kc*512 : 0);
        const char* ga = (const char*)A + (arow*K + k0)*2 + sls_[i]*16;
        __builtin_amdgcn_global_load_lds((gv1*)ga, (lv3*)&As[(w*256 + i*64)*8], 16, 0, 0);
        int brow = n0 + rows_[i] + tapoff;
        if (TAPPED) brow = brow < 0 ? 0 : (brow > SS-1 ? SS-1 : brow);
        const char* gb = Bb + (long)brow*ldbB + c0*2 + sls_[i]*16;
        __builtin_amdgcn_global_load_lds((gv1*)gb, (lv3*)&Bs[(w*256 + i*64)*8], 16, 0, 0);
      }
      __syncthreads();
      #pragma unroll
      for (int kk = 0; kk < 2; kk++){
        bf16x8 af[4], bf[4];
        #pragma unroll
        for (int f = 0; f < 4; f++){
          int rowa = wr*64 + f*16 + col;
          int sla = (g + kk*4) ^ (rowa & 7);
          af[f] = *(const bf16x8*)&As[rowa*64 + sla*8];
          int rowb = wc*64 + f*16 + col;
          int slb = (g + kk*4) ^ (rowb & 7);
          bf[f] = *(const bf16x8*)&Bs[rowb*64 + slb*8];
        }
        #pragma unroll
        for (int fm = 0; fm < 4; fm++)
          #pragma unroll
          for (int fn = 0; fn < 4; fn++)
            acc[fm][fn] = __builtin_amdgcn_mfma_f32_16x16x32_bf16(af[fm], bf[fn], acc[fm][fn], 0, 0, 0);
      }
    }

    if (EPI == 4){
      #pragma unroll
      for (int fm = 0; fm < 4; fm++){
        const int mm_l = wr*64 + fm*16 + g*4;
        float bb[4];
        #pragma unroll
        for (int r = 0; r < 4; r++) bb[r] = bias[kc*512 + m00 + mm_l + r];
        #pragma unroll
        for (int fn = 0; fn < 4; fn++){
          float p = psh[kc*128 + wc*64 + fn*16 + col];
          #pragma unroll
          for (int r = 0; r < 4; r++)
            facc[fm][fn][r] += p * (acc[fm][fn][r] + bb[r]);
        }
      }
    }
  }

  __syncthreads();
  US* tile = shb;
  #pragma unroll
  for (int fm = 0; fm < 4; fm++){
    const int mm_l = wr*64 + fm*16 + g*4;
    float bb[4];
    if (EPI == 0 || EPI == 2 || EPI == 3 || EPI == 6){
      #pragma unroll
      for (int r = 0; r < 4; r++) bb[r] = bias[m00 + mm_l + r];
    }
    #pragma unroll
    for (int fn = 0; fn < 4; fn++){
      const int nn_l = wc*64 + fn*16 + col;
      f32x4 v = (EPI == 4) ? facc[fm][fn] : acc[fm][fn];
      if (EPI == 5){
        #pragma unroll
        for (int r = 0; r < 4; r++){
          int row = mm_l + r;
          int byte = row*256 + ((nn_l*2) ^ ((row & 7) << 4));
          *(US*)((char*)tile + byte) = f2b(v[r]);
        }
      } else {
        US pk[4];
        #pragma unroll
        for (int r = 0; r < 4; r++){
          float val = v[r];
          if (EPI != 4) val += bb[r];
          if (EPI == 2){ int m = m00 + mm_l + r; val = val*(s1v[m]*0.99999500f) + s2v[m]; val = val/(1.f + expf(-val)); }
          if (EPI == 3){ val = val/(1.f + expf(-val)); }
          pk[r] = f2b(val);
        }
        int byte = nn_l*256 + ((mm_l*2) ^ ((nn_l & 7) << 4));
        *(int2*)((char*)tile + byte) = *(int2*)pk;
      }
    }
  }
  __syncthreads();
  const int r0 = tid >> 4, c = tid & 15;
  const int isf = (EPI == 6) ? fl[0] : 0;
  #pragma unroll
  for (int p = 0; p < 8; p++){
    int r = p*16 + r0;
    int4 vv = *(const int4*)((const char*)tile + r*256 + ((c*16) ^ ((r & 7) << 4)));
    long obase = (EPI == 5) ? ((long)b*sOut + (long)(m00 + r)*ldo + n0)
                            : ((long)b*sOut + (long)(n0 + r)*ldo + m00);
    *(int4*)((US*)Out + obase + c*8) = vv;
    if (EPI == 6){
      long eb = obase + c*8;
      const US* vp = (const US*)&vv;
      US dpk[8], lpk[8];
      #pragma unroll
      for (int q = 0; q < 8; q++){
        float sv = b2sf(vp[q]);
        float xv = rd(xres, eb + q, isf);
        dpk[q] = f2b(xv - sv);
        lpk[q] = f2b(sv/(1.f + expf(-sv)));
      }
      *(int4*)&aux1[eb] = *(int4*)dpk;
      *(int4*)&aux2[eb] = *(int4*)lpk;
    }
  }
}

__global__ __launch_bounds__(256) void k_pool1(const US* __restrict__ h2, float* __restrict__ part){
  int blk = blockIdx.x;
  int b = blk >> 3, ch = blk & 7;
  int c = threadIdx.x;
  float s = 0.f;
  for (int t = ch*128; t < ch*128 + 128; t++) s += b2sf(h2[((long)(b*SS + t))*HD + c]);
  part[(blk << 8) | c] = s;
}
__global__ __launch_bounds__(256) void k_pool2(const float* __restrict__ part, float* __restrict__ feat){
  int b = blockIdx.x, c = threadIdx.x;
  float s = 0.f;
  for (int ch = 0; ch < 8; ch++) s += part[((b*8 + ch) << 8) | c];
  feat[b*HD + c] = s * (1.f/SS);
}
__global__ void k_params(const float* __restrict__ feat, const float* __restrict__ pw,
                         const float* __restrict__ pb, float* __restrict__ dynA, float* __restrict__ dynB){
  int t = threadIdx.x;
  if (t >= 128) return;
  int b = t >> 3, j = t & 7;
  float s = pb[j];
  for (int c = 0; c < HD; c++) s += feat[b*HD + c]*pw[j*HD + c];
  int k = j >> 1;
  if ((j & 1) == 0){
    float sp = s > 20.f ? s : log1pf(expf(s));
    dynA[b*4 + k] = sp + 0.01f;
  } else {
    dynB[b*4 + k] = 1024.f/(1.f + expf(-s));
  }
}
__global__ void k_psi(const float* __restrict__ dynA, const float* __restrict__ dynB, float* __restrict__ psi){
  int i = blockIdx.x*256 + threadIdx.x;
  if (i >= NB*4*SS) return;
  int b = i >> 12, k = (i >> 10) & 3, s = i & (SS-1);
  float u = ((float)s - dynB[b*4 + k]) / dynA[b*4 + k];
  psi[i] = 0.86732507f*(1.f - u*u)*expf(-0.5f*u*u);
}
__global__ __launch_bounds__(128) void k_final(const US* __restrict__ base, const US* __restrict__ kan,
    const US* __restrict__ gate, const void* __restrict__ x,
    void* __restrict__ out, const float* __restrict__ lng, const float* __restrict__ lnb,
    const int* __restrict__ fl){
  int isf = fl[0];
  long row = blockIdx.x;
  int t = threadIdx.x;
  long off = row*DD + t*4;
  ushort4 bs = *(const ushort4*)&base[off];
  ushort4 gt = *(const ushort4*)&gate[off];
  ushort4 kn = *(const ushort4*)&kan[off];
  float xv[4];
  if (isf){ float4 q = *(const float4*)((const float*)x + off); xv[0]=q.x; xv[1]=q.y; xv[2]=q.z; xv[3]=q.w; }
  else { ushort4 q = *(const ushort4*)((const US*)x + off); xv[0]=b2sf(q.x); xv[1]=b2sf(q.y); xv[2]=b2sf(q.z); xv[3]=b2sf(q.w); }
  float bv[4] = {b2sf(bs.x), b2sf(bs.y), b2sf(bs.z), b2sf(bs.w)};
  float gv[4] = {b2sf(gt.x), b2sf(gt.y), b2sf(gt.z), b2sf(gt.w)};
  const US* kp = (const US*)&kn;
  float y[4];
  float sm = 0.f, ssq = 0.f;
  #pragma unroll
  for (int r = 0; r < 4; r++){
    float amp = 2.f/(1.f + expf(-gv[r]));
    y[r] = bv[r] + b2sf(kp[r])*amp + xv[r];
    sm += y[r]; ssq += y[r]*y[r];
  }
  for (int o = 32; o; o >>= 1){ sm += __shfl_down(sm, o); ssq += __shfl_down(ssq, o); }
  __shared__ float sh[4];
  int lane = t & 63, wid = t >> 6;
  if (lane == 0){ sh[wid*2] = sm; sh[wid*2+1] = ssq; }
  __syncthreads();
  float S1 = sh[0] + sh[2], S2 = sh[1] + sh[3];
  float mean = S1*(1.f/DD), var = S2*(1.f/DD) - mean*mean;
  float rstd = rsqrtf(var + 1e-5f);
  #pragma unroll
  for (int r = 0; r < 4; r++){
    int d = t*4 + r;
    float val = (y[r] - mean)*rstd*lng[d] + lnb[d];
    if (isf) ((float*)out)[off + r] = val;
    else     ((US*)out)[off + r] = f2b(val);
  }
}

extern "C" void kernel_launch(void* const* d_in, const int* in_sizes, int n_in,
                              void* d_out, int out_size, void* d_ws, size_t ws_size,
                              hipStream_t stream){
  const void* x       = d_in[0];
  const void* conv_w  = d_in[1];
  const void* conv_b  = d_in[2];
  const void* fusion_w= d_in[3];
  const void* fusion_b= d_in[4];
  const void* refine_w= d_in[5];
  const void* refine_b= d_in[6];
  const void* hyp1_w  = d_in[7];
  const void* hyp1_b  = d_in[8];
  const void* bn_g    = d_in[9];
  const void* bn_b    = d_in[10];
  const void* hyp2_w  = d_in[11];
  const void* hyp2_b  = d_in[12];
  const void* proj_w  = d_in[13];
  const void* proj_b  = d_in[14];
  const void* gate_w  = d_in[15];
  const void* gate_b  = d_in[16];
  const void* base_w  = d_in[17];
  const void* base_b  = d_in[18];
  const void* wav_w   = d_in[19];
  const void* wav_b   = d_in[20];
  const void* ln_g    = d_in[21];
  const void* ln_b    = d_in[22];

  char* wsb = (char*)d_ws;
  long off = 0;
  auto AA = [&](long bytes)->char*{ char* p = wsb + off; off += (bytes + 255) & ~255L; return p; };
  US* smA   = (US*)AA((long)NB*SS*DD*2);
  US* smB   = (US*)AA((long)NB*SS*DD*2);
  US* xTh   = (US*)AA((long)NB*SS*DD*2);
  US* cc    = (US*)AA((long)NB*SS*2048*2);
  US* baseB = (US*)AA((long)NB*SS*DD*2);
  US* WBLK  = (US*)AA(7733248L*2);
  US* Cm    = (US*)AA(1024L*1024*2);
  float* gvec = (float*)AA(1024*4);
  float* FBLK = (float*)AA(11016L*4);
  float* feat = (float*)AA(16*256*4);
  float* part = (float*)AA(16*8*256*4);
  float* dynA = (float*)AA(64*4);
  float* dynB = (float*)AA(64*4);
  float* psi  = (float*)AA((long)NB*4*SS*4);
  int* flag   = (int*)AA(64);
  if ((size_t)off > ws_size) return;

  US* Wc  = WBLK;
  US* Wr  = Wc  + 3145728L;
  US* Wh1 = Wr  + 786432L;
  US* Wh2 = Wh1 + 786432L;
  US* Wwv = Wh2 + 393216L;
  US* Fw  = Wwv + 1048576L;
  US* BW  = Fw  + 1048576L;
  US* GW  = BW  + 262144L;
  float* cb_f = FBLK;
  float* fz_b = cb_f + 2048;
  float* rf_b = fz_b + 512;
  float* h1_b = rf_b + 512;
  float* h2_b = h1_b + 512;
  float* bs_b = h2_b + 256;
  float* gt_b = bs_b + 512;
  float* wv_b = gt_b + 512;
  float* bngf = wv_b + 2048;
  float* bnbf = bngf + 512;
  float* pwf  = bnbf + 512;
  float* pbf  = pwf  + 2048;
  float* lngf = pbf  + 8;
  float* lnbf = lngf + 512;
  US* spike = cc;
  US* baseO = cc + 8388608L;
  US* kanb  = cc + 16777216L;
  US* h2b   = cc + 25165824L;

  auto g1 = [](long n){ return dim3((unsigned)((n + 255)/256)); };
  const long sAct = (long)SS*DD*2;
  const long sCC  = (long)SS*2048*2;
  const long oAct = (long)SS*DD;
  const long oCC  = (long)SS*2048;
  const long oH2  = (long)SS*HD;

  k_detect<<<1, 256, 0, stream>>>(x, flag);

  { WTab wt;
    const void* srcs[8] = {conv_w, refine_w, hyp1_w, hyp2_w, wav_w, fusion_w, base_w, gate_w};
    long sizes[8] = {3145728, 786432, 786432, 393216, 1048576, 1048576, 262144, 262144};
    int types[8] = {0,0,0,0,1,2,2,2};
    int Cs[8]    = {512,512,512,512,0,0,0,0};
    long acc_ = 0;
    for (int i = 0; i < 8; i++){ wt.src[i]=srcs[i]; wt.start[i]=acc_; wt.type[i]=types[i]; wt.C[i]=Cs[i]; acc_ += sizes[i]; }
    wt.start[8] = acc_;
    k_prep_w<<<g1(acc_), 256, 0, stream>>>(wt, WBLK, flag);
  }
  { FTab ft;
    const void* srcs[14] = {conv_b, fusion_b, refine_b, hyp1_b, hyp2_b, base_b, gate_b,
                            wav_b, bn_g, bn_b, proj_w, proj_b, ln_g, ln_b};
    int sizes[14] = {2048,512,512,512,256,512,512,2048,512,512,2048,8,512,512};
    int acc_ = 0;
    for (int i = 0; i < 14; i++){ ft.src[i]=srcs[i]; ft.start[i]=acc_; acc_ += sizes[i]; }
    ft.start[14] = acc_;
    k_cvt_all<<<g1(acc_), 256, 0, stream>>>(ft, FBLK, flag);
  }
  k_build_g<<<g1(SS), 256, 0, stream>>>(gvec);
  k_build_cmat<<<g1((long)SS*SS), 256, 0, stream>>>(gvec, Cm);
  k_transpose_b<<<dim3(SS/32, DD/32, NB), 256, 0, stream>>>(x, xTh, flag);

  // circulant low-pass: smA[b][s][d]
  k_mfma<5,false><<<dim3(4*NB, 8), 256, 0, stream>>>(Cm, xTh, smA,
      4, 1024, (long)DD*SS*2, SS*2, 0, oAct, DD,
      nullptr, nullptr, nullptr, nullptr, nullptr, nullptr, nullptr, nullptr);

  // it 0: register-pipelined conv -> fusion
  k_pipe<1,true><<<dim3(8*NB, 16), 256, 0, stream>>>(Wc, smA, cc,
      8, 1536, sAct, DD*2, -1, oCC, 2048, cb_f);
  k_mfma<0,false><<<dim3(8*NB, 4), 256, 0, stream>>>(Fw, cc, smB,
      8, 2048, sCC, 4096, 0, oAct, DD,
      fz_b, nullptr, nullptr, nullptr, nullptr, nullptr, nullptr, nullptr);
  // it 1: conv -> fusion (+fused diff & silu)
  k_pipe<1,true><<<dim3(8*NB, 16), 256, 0, stream>>>(Wc, smB, cc,
      8, 1536, sAct, DD*2, -1, oCC, 2048, cb_f);
  k_mfma<6,false><<<dim3(8*NB, 4), 256, 0, stream>>>(Fw, cc, smA,
      8, 2048, sCC, 4096, 0, oAct, DD,
      fz_b, nullptr, nullptr, nullptr, x, smB, baseB, flag);

  // spike = refine(diff)
  k_mfma<0,true><<<dim3(8*NB, 4), 256, 0, stream>>>(Wr, smB, spike,
      8, 1536, sAct, DD*2, 1, oAct, DD,
      rf_b, nullptr, nullptr, nullptr, nullptr, nullptr, nullptr, nullptr);

  // hypernet
  k_mfma<2,true><<<dim3(8*NB, 4), 256, 0, stream>>>(Wh1, smA, xTh,
      8, 1536, sAct, DD*2, 1, oAct, DD,
      h1_b, bngf, bnbf, nullptr, nullptr, nullptr, nullptr, nullptr);
  k_mfma<3,true><<<dim3(8*NB, 2), 256, 0, stream>>>(Wh2, xTh, h2b,
      8, 1536, sAct, DD*2, 1, oH2, HD,
      h2_b, nullptr, nullptr, nullptr, nullptr, nullptr, nullptr, nullptr);
  k_pool1<<<NB*8, 256, 0, stream>>>(h2b, part);
  k_pool2<<<NB, 256, 0, stream>>>(part, feat);
  k_params<<<1, 128, 0, stream>>>(feat, pwf, pbf, dynA, dynB);
  k_psi<<<g1(NB*4*SS), 256, 0, stream>>>(dynA, dynB, psi);

  // base / gate
  k_mfma<0,false><<<dim3(8*NB, 4), 256, 0, stream>>>(BW, baseB, baseO,
      8, 512, sAct, DD*2, 0, oAct, DD,
      bs_b, nullptr, nullptr, nullptr, nullptr, nullptr, nullptr, nullptr);
  k_mfma<0,false><<<dim3(8*NB, 4), 256, 0, stream>>>(GW, baseO, xTh,
      8, 512, sAct, DD*2, 0, oAct, DD,
      gt_b, nullptr, nullptr, nullptr, nullptr, nullptr, nullptr, nullptr);

  // psi-fused wavelet
  k_mfma<4,false><<<dim3(8*NB, 4), 256, 0, stream>>>(Wwv, spike, kanb,
      8, 512, sAct, DD*2, 0, oAct, DD,
      wv_b, nullptr, nullptr, psi, nullptr, nullptr, nullptr, nullptr);

  // combine + residual + LayerNorm
  k_final<<<NB*SS, 128, 0, stream>>>(baseO, kanb, xTh, x, d_out, lngf, lnbf, flag);
}

// Round 15
// 660.090 us; speedup vs baseline: 1.0520x; 1.0520x over previous
//
#include <hip/hip_runtime.h>
#include <hip/hip_bf16.h>
#include <math.h>

#define NB 16
#define SS 1024
#define DD 512
#define HD 256

typedef unsigned short US;
typedef short bf16x8 __attribute__((ext_vector_type(8)));
typedef float f32x4 __attribute__((ext_vector_type(4)));
typedef __attribute__((address_space(1))) const void gv1;
typedef __attribute__((address_space(3))) void lv3;

static __device__ __forceinline__ float b2sf(US u){ return __uint_as_float(((unsigned)u)<<16); }
static __device__ __forceinline__ US f2b(float f){
  __hip_bfloat16 h = __float2bfloat16(f);
  union { __hip_bfloat16 h; US u; } c; c.h = h; return c.u;
}
static __device__ __forceinline__ float rd(const void* __restrict__ p, long i, int isf){
  return isf ? ((const float*)p)[i] : b2sf(((const US*)p)[i]);
}

__global__ void k_detect(const void* __restrict__ x, int* __restrict__ flag){
  const US* u = (const US*)x;
  int t = threadIdx.x;
  float m = 0.f;
  for (int i = t; i < 4096; i += 256){
    float v = fabsf(b2sf(u[i]));
    if (isnan(v) || isinf(v)) v = 1e30f;
    m = fmaxf(m, v);
  }
  for (int off = 32; off; off >>= 1) m = fmaxf(m, __shfl_down(m, off));
  __shared__ float sh[4];
  if ((t & 63) == 0) sh[t >> 6] = m;
  __syncthreads();
  if (t == 0){
    float mm = fmaxf(fmaxf(sh[0], sh[1]), fmaxf(sh[2], sh[3]));
    flag[0] = (mm > 1e6f) ? 1 : 0;
  }
}

struct WTab { const void* src[8]; long start[9]; int type[8]; int C[8]; };
__global__ void k_prep_w(WTab wt, US* __restrict__ dst, const int* __restrict__ fl){
  int isf = fl[0];
  long i = (long)blockIdx.x*256 + threadIdx.x;
  if (i >= wt.start[8]) return;
  int s = 0;
  while (i >= wt.start[s+1]) s++;
  long r = i - wt.start[s];
  long si;
  if (wt.type[s] == 0){
    int C = wt.C[s]; long oc3 = 3L*C;
    int o = (int)(r / oc3); int rr = (int)(r - (long)o*oc3); int t = rr / C; int c = rr - t*C;
    si = ((long)o*C + c)*3 + t;
  } else if (wt.type[s] == 1){
    int k = (int)(r >> 18); int e = (int)((r >> 9) & 511); int d = (int)(r & 511);
    si = ((long)(k*512 + d))*512 + e;
  } else si = r;
  dst[i] = f2b(rd(wt.src[s], si, isf));
}

struct FTab { const void* src[14]; int start[15]; };
__global__ void k_cvt_all(FTab ft, float* __restrict__ dst, const int* __restrict__ fl){
  int isf = fl[0];
  int i = blockIdx.x*256 + threadIdx.x;
  if (i >= ft.start[14]) return;
  int s = 0;
  while (i >= ft.start[s+1]) s++;
  dst[i] = rd(ft.src[s], i - ft.start[s], isf);
}

__global__ void k_build_g(float* __restrict__ g){
  int d = blockIdx.x*256 + threadIdx.x;
  if (d >= SS) return;
  float s = 1.f;
  for (int k = 1; k < 102; ++k){
    int r = (k*d) & (SS-1);
    s += 2.f * cosf(6.28318530718f * (float)r * (1.f/SS));
  }
  g[d] = s * (1.f/SS);
}
__global__ void k_build_cmat(const float* __restrict__ g, US* __restrict__ cm){
  int i = blockIdx.x*256 + threadIdx.x;
  if (i >= SS*SS) return;
  int t = i >> 10, s = i & (SS-1);
  cm[i] = f2b(g[(s - t) & (SS-1)]);
}
__global__ __launch_bounds__(256) void k_transpose_b(const void* __restrict__ x, US* __restrict__ xt, const int* __restrict__ fl){
  int isf = fl[0];
  __shared__ float tl[32][33];
  int b = blockIdx.z, s0 = blockIdx.x*32, d0 = blockIdx.y*32;
  int tx = threadIdx.x & 31, ty = threadIdx.x >> 5;
  for (int i = ty; i < 32; i += 8)
    tl[i][tx] = rd(x, ((long)(b*SS + s0+i))*DD + d0+tx, isf);
  __syncthreads();
  for (int i = ty; i < 32; i += 8)
    xt[((long)(b*DD + d0+i))*SS + s0+tx] = f2b(tl[tx][i]);
}

// ---------------- 256x256 MFMA GEMM, K-slice ring, ONE barrier per 32-K slice ----------------
template<int EPI, bool TAPPED>
__global__ __launch_bounds__(512, 2) void k_mfma8(
    const US* __restrict__ A, const US* __restrict__ Bact, void* __restrict__ Out,
    int NYB, int K, long sBbytes, int ldbB, int dil,
    long sOut, int ldo, const float* __restrict__ bias)
{
  __shared__ US ring[65536];   // 128 KiB
  const int bx = blockIdx.x;
  const int ny = bx % NYB, b = bx / NYB;
  const int m0 = blockIdx.y*256, n0 = ny*256;
  const int dd = (TAPPED && dil < 0) ? (1 << (m0 >> 9)) : dil;
  const char* Bb = (const char*)Bact + (long)b*sBbytes;
  const int tid = threadIdx.x;
  const int lane = tid & 63, w = tid >> 6;
  const int wm = w >> 2, wn = w & 3;
  const int col = lane & 15, g = lane >> 4;
  const int NTs = K >> 5;

  int offA[8], offB[4];
  #pragma unroll
  for (int fm = 0; fm < 8; fm++){
    int r = wm*128 + fm*16 + col;
    int R = r >> 1;
    int wg = ((r & 1) << 2) | g;
    offA[fm] = R*128 + ((wg ^ (R & 7)) << 4);
  }
  #pragma unroll
  for (int fn = 0; fn < 4; fn++){
    int r = wn*64 + fn*16 + col;
    int R = r >> 1;
    int wg = ((r & 1) << 2) | g;
    offB[fn] = R*128 + ((wg ^ (R & 7)) << 4);
  }
  int rl[2], gg[2];
  #pragma unroll
  for (int j = 0; j < 2; j++){
    int c = (w*2 + j)*64 + lane;
    int R = c >> 3, f = c & 7;
    int wg = f ^ (R & 7);
    rl[j] = 2*R + (wg >> 2);
    gg[j] = wg & 3;
  }

  auto stageA = [&](int t){
    int slot = t & 3, kb = t << 5;
    #pragma unroll
    for (int j = 0; j < 2; j++){
      const char* ga = (const char*)A + ((long)(m0 + rl[j])*K + kb + gg[j]*8)*2;
      __builtin_amdgcn_global_load_lds((gv1*)ga, (lv3*)&ring[slot*8192 + (w*2 + j)*512], 16, 0, 0);
    }
  };
  auto stageB = [&](int t){
    int slot = t & 3, kb = t << 5;
    int c0 = TAPPED ? (kb & 511) : kb;
    int tapoff = TAPPED ? (((kb >> 9) - 1)*dd) : 0;
    #pragma unroll
    for (int j = 0; j < 2; j++){
      int brow = n0 + rl[j] + tapoff;
      if (TAPPED) brow = brow < 0 ? 0 : (brow > SS-1 ? SS-1 : brow);
      const char* gb = Bb + (long)brow*ldbB + (c0 + gg[j]*8)*2;
      __builtin_amdgcn_global_load_lds((gv1*)gb, (lv3*)&ring[32768 + slot*8192 + (w*2 + j)*512], 16, 0, 0);
    }
  };

  f32x4 acc[8][4];
  #pragma unroll
  for (int i = 0; i < 8; i++)
    #pragma unroll
    for (int j = 0; j < 4; j++) acc[i][j] = (f32x4){0.f,0.f,0.f,0.f};

  stageA(0); stageB(0);
  if (NTs > 1){ stageA(1); stageB(1); }
  if (NTs > 2) stageA(2);
  asm volatile("s_waitcnt vmcnt(6)" ::: "memory");
  __builtin_amdgcn_s_barrier();

  bf16x8 af[4], af2[4], bf[4];
  for (int ks = 0; ks < NTs; ++ks){
    const char* As = (const char*)&ring[(ks & 3)*8192];
    const char* Bs = (const char*)&ring[32768 + (ks & 3)*8192];
    #pragma unroll
    for (int fn = 0; fn < 4; fn++) bf[fn] = *(const bf16x8*)(Bs + offB[fn]);
    #pragma unroll
    for (int fm = 0; fm < 4; fm++) af[fm] = *(const bf16x8*)(As + offA[fm]);
    if (ks + 2 < NTs) stageB(ks + 2);
    __builtin_amdgcn_s_setprio(1);
    #pragma unroll
    for (int fm = 0; fm < 4; fm++)
      #pragma unroll
      for (int fn = 0; fn < 4; fn++)
        acc[fm][fn] = __builtin_amdgcn_mfma_f32_16x16x32_bf16(af[fm], bf[fn], acc[fm][fn], 0, 0, 0);
    __builtin_amdgcn_s_setprio(0);
    #pragma unroll
    for (int fm = 0; fm < 4; fm++) af2[fm] = *(const bf16x8*)(As + offA[4 + fm]);
    if (ks + 3 < NTs) stageA(ks + 3);
    __builtin_amdgcn_s_setprio(1);
    #pragma unroll
    for (int fm = 0; fm < 4; fm++)
      #pragma unroll
      for (int fn = 0; fn < 4; fn++)
        acc[4 + fm][fn] = __builtin_amdgcn_mfma_f32_16x16x32_bf16(af2[fm], bf[fn], acc[4 + fm][fn], 0, 0, 0);
    __builtin_amdgcn_s_setprio(0);
    if (ks < NTs - 3)       asm volatile("s_waitcnt vmcnt(6)" ::: "memory");
    else if (ks == NTs - 3) asm volatile("s_waitcnt vmcnt(4)" ::: "memory");
    else if (ks == NTs - 2) asm volatile("s_waitcnt vmcnt(0)" ::: "memory");
    __builtin_amdgcn_s_barrier();
  }

  US* tile = ring;
  #pragma unroll
  for (int fm = 0; fm < 8; fm++){
    int m_l = wm*128 + fm*16 + g*4;
    float4 bb = *(const float4*)&bias[m0 + m_l];
    const float* bp = (const float*)&bb;
    #pragma unroll
    for (int fn = 0; fn < 4; fn++){
      int n_l = wn*64 + fn*16 + col;
      f32x4 v = acc[fm][fn];
      US pk[4];
      #pragma unroll
      for (int r = 0; r < 4; r++){
        float val = v[r] + bp[r];
        if (EPI == 1) val = 0.5f*val*(1.f + erff(val*0.70710678f));
        pk[r] = f2b(val);
      }
      long byte = (long)n_l*512 + ((((m_l >> 3) ^ (n_l & 7)) << 4) | ((m_l & 7)*2));
      *(int2*)((char*)tile + byte) = *(int2*)pk;
    }
  }
  __syncthreads();
  #pragma unroll
  for (int p = 0; p < 16; p++){
    int chunk = p*512 + tid;
    int rr = chunk >> 5, cg = chunk & 31;
    int4 vv = *(const int4*)((const char*)tile + (long)rr*512 + ((cg ^ (rr & 7)) << 4));
    *(int4*)((US*)Out + (long)b*sOut + (long)(n0 + rr)*ldo + m0 + cg*8) = vv;
  }
}

// ---------------- 128x128 MFMA GEMM ----------------
// EPI: 0=bias store out[b][n][m]; 2=+bn+silu; 3=+silu; 4=wavelet-fused;
//      5=NT store out[b][m][n]; 6=bias store + aux1=x-val + aux2=silu(val).
template<int EPI, bool TAPPED>
__global__ __launch_bounds__(256) void k_mfma(
    const US* __restrict__ A, const US* __restrict__ Bact, void* __restrict__ Out,
    int NYB, int K, long sBbytes, int ldbB, int dil,
    long sOut, int ldo,
    const float* __restrict__ bias, const float* __restrict__ s1v, const float* __restrict__ s2v,
    const float* __restrict__ psiP, const void* __restrict__ xres,
    US* __restrict__ aux1, US* __restrict__ aux2, const int* __restrict__ fl)
{
  __shared__ alignas(16) US shb[2*128*64];
  __shared__ float psh[(EPI==4) ? 512 : 4];
  US* As = shb;
  US* Bs = shb + 128*64;
  const int bx = blockIdx.x;
  const int ny = bx % NYB;
  const int b  = bx / NYB;
  const int m00 = blockIdx.y*128, n0 = ny*128;
  const int dd = (TAPPED && dil < 0) ? (1 << (m00 >> 9)) : dil;
  const char* Bb = (const char*)Bact + (long)b*sBbytes;
  const int tid = threadIdx.x;
  const int lane = tid & 63, w = tid >> 6;
  const int wr = w >> 1, wc = w & 1;
  const int col = lane & 15, g = lane >> 4;

  if (EPI == 4){
    for (int i = tid; i < 512; i += 256)
      psh[i] = psiP[(long)b*4096 + (i >> 7)*SS + n0 + (i & 127)];
  }

  f32x4 acc[4][4];
  f32x4 facc[4][4];
  if (EPI == 4){
    #pragma unroll
    for (int i = 0; i < 4; i++)
      #pragma unroll
      for (int j = 0; j < 4; j++) facc[i][j] = (f32x4){0.f,0.f,0.f,0.f};
  }

  int rows_[4], sls_[4];
  #pragma unroll
  for (int i = 0; i < 4; i++){
    int c = w*256 + i*64 + lane;
    rows_[i] = c >> 3;
    sls_[i] = (c & 7) ^ ((c >> 3) & 7);
  }

  const int NKC = (EPI == 4) ? 4 : 1;
  for (int kc = 0; kc < NKC; ++kc){
    #pragma unroll
    for (int i = 0; i < 4; i++)
      #pragma unroll
      for (int j = 0; j < 4; j++) acc[i][j] = (f32x4){0.f,0.f,0.f,0.f};

    for (int k0 = 0; k0 < K; k0 += 64){
      const int c0 = TAPPED ? (k0 & 511) : k0;
      const int tapoff = TAPPED ? (((k0 >> 9) - 1)*dd) : 0;
      __syncthreads();
      #pragma unroll
      for (int i = 0; i < 4; i++){
        const long arow = (long)(m00 + rows_[i]) + (EPI==4 ? kc*512 : 0);
        const char* ga = (const char*)A + (arow*K + k0)*2 + sls_[i]*16;
        __builtin_amdgcn_global_load_lds((gv1*)ga, (lv3*)&As[(w*256 + i*64)*8], 16, 0, 0);
        int brow = n0 + rows_[i] + tapoff;
        if (TAPPED) brow = brow < 0 ? 0 : (brow > SS-1 ? SS-1 : brow);
        const char* gb = Bb + (long)brow*ldbB + c0*2 + sls_[i]*16;
        __builtin_amdgcn_global_load_lds((gv1*)gb, (lv3*)&Bs[(w*256 + i*64)*8], 16, 0, 0);
      }
      __syncthreads();
      #pragma unroll
      for (int kk = 0; kk < 2; kk++){
        bf16x8 af[4], bf[4];
        #pragma unroll
        for (int f = 0; f < 4; f++){
          int rowa = wr*64 + f*16 + col;
          int sla = (g + kk*4) ^ (rowa & 7);
          af[f] = *(const bf16x8*)&As[rowa*64 + sla*8];
          int rowb = wc*64 + f*16 + col;
          int slb = (g + kk*4) ^ (rowb & 7);
          bf[f] = *(const bf16x8*)&Bs[rowb*64 + slb*8];
        }
        #pragma unroll
        for (int fm = 0; fm < 4; fm++)
          #pragma unroll
          for (int fn = 0; fn < 4; fn++)
            acc[fm][fn] = __builtin_amdgcn_mfma_f32_16x16x32_bf16(af[fm], bf[fn], acc[fm][fn], 0, 0, 0);
      }
    }

    if (EPI == 4){
      #pragma unroll
      for (int fm = 0; fm < 4; fm++){
        const int mm_l = wr*64 + fm*16 + g*4;
        float bb[4];
        #pragma unroll
        for (int r = 0; r < 4; r++) bb[r] = bias[kc*512 + m00 + mm_l + r];
        #pragma unroll
        for (int fn = 0; fn < 4; fn++){
          float p = psh[kc*128 + wc*64 + fn*16 + col];
          #pragma unroll
          for (int r = 0; r < 4; r++)
            facc[fm][fn][r] += p * (acc[fm][fn][r] + bb[r]);
        }
      }
    }
  }

  __syncthreads();
  US* tile = shb;
  #pragma unroll
  for (int fm = 0; fm < 4; fm++){
    const int mm_l = wr*64 + fm*16 + g*4;
    float bb[4];
    if (EPI == 0 || EPI == 2 || EPI == 3 || EPI == 6){
      #pragma unroll
      for (int r = 0; r < 4; r++) bb[r] = bias[m00 + mm_l + r];
    }
    #pragma unroll
    for (int fn = 0; fn < 4; fn++){
      const int nn_l = wc*64 + fn*16 + col;
      f32x4 v = (EPI == 4) ? facc[fm][fn] : acc[fm][fn];
      if (EPI == 5){
        #pragma unroll
        for (int r = 0; r < 4; r++){
          int row = mm_l + r;
          int byte = row*256 + ((nn_l*2) ^ ((row & 7) << 4));
          *(US*)((char*)tile + byte) = f2b(v[r]);
        }
      } else {
        US pk[4];
        #pragma unroll
        for (int r = 0; r < 4; r++){
          float val = v[r];
          if (EPI != 4) val += bb[r];
          if (EPI == 2){ int m = m00 + mm_l + r; val = val*(s1v[m]*0.99999500f) + s2v[m]; val = val/(1.f + expf(-val)); }
          if (EPI == 3){ val = val/(1.f + expf(-val)); }
          pk[r] = f2b(val);
        }
        int byte = nn_l*256 + ((mm_l*2) ^ ((nn_l & 7) << 4));
        *(int2*)((char*)tile + byte) = *(int2*)pk;
      }
    }
  }
  __syncthreads();
  const int r0 = tid >> 4, c = tid & 15;
  const int isf = (EPI == 6) ? fl[0] : 0;
  #pragma unroll
  for (int p = 0; p < 8; p++){
    int r = p*16 + r0;
    int4 vv = *(const int4*)((const char*)tile + r*256 + ((c*16) ^ ((r & 7) << 4)));
    long obase = (EPI == 5) ? ((long)b*sOut + (long)(m00 + r)*ldo + n0)
                            : ((long)b*sOut + (long)(n0 + r)*ldo + m00);
    *(int4*)((US*)Out + obase + c*8) = vv;
    if (EPI == 6){
      long eb = obase + c*8;
      const US* vp = (const US*)&vv;
      US dpk[8], lpk[8];
      #pragma unroll
      for (int q = 0; q < 8; q++){
        float sv = b2sf(vp[q]);
        float xv = rd(xres, eb + q, isf);
        dpk[q] = f2b(xv - sv);
        lpk[q] = f2b(sv/(1.f + expf(-sv)));
      }
      *(int4*)&aux1[eb] = *(int4*)dpk;
      *(int4*)&aux2[eb] = *(int4*)lpk;
    }
  }
}

__global__ __launch_bounds__(256) void k_pool1(const US* __restrict__ h2, float* __restrict__ part){
  int blk = blockIdx.x;
  int b = blk >> 3, ch = blk & 7;
  int c = threadIdx.x;
  float s = 0.f;
  for (int t = ch*128; t < ch*128 + 128; t++) s += b2sf(h2[((long)(b*SS + t))*HD + c]);
  part[(blk << 8) | c] = s;
}
__global__ __launch_bounds__(256) void k_pool2(const float* __restrict__ part, float* __restrict__ feat){
  int b = blockIdx.x, c = threadIdx.x;
  float s = 0.f;
  for (int ch = 0; ch < 8; ch++) s += part[((b*8 + ch) << 8) | c];
  feat[b*HD + c] = s * (1.f/SS);
}
__global__ void k_params(const float* __restrict__ feat, const float* __restrict__ pw,
                         const float* __restrict__ pb, float* __restrict__ dynA, float* __restrict__ dynB){
  int t = threadIdx.x;
  if (t >= 128) return;
  int b = t >> 3, j = t & 7;
  float s = pb[j];
  for (int c = 0; c < HD; c++) s += feat[b*HD + c]*pw[j*HD + c];
  int k = j >> 1;
  if ((j & 1) == 0){
    float sp = s > 20.f ? s : log1pf(expf(s));
    dynA[b*4 + k] = sp + 0.01f;
  } else {
    dynB[b*4 + k] = 1024.f/(1.f + expf(-s));
  }
}
__global__ void k_psi(const float* __restrict__ dynA, const float* __restrict__ dynB, float* __restrict__ psi){
  int i = blockIdx.x*256 + threadIdx.x;
  if (i >= NB*4*SS) return;
  int b = i >> 12, k = (i >> 10) & 3, s = i & (SS-1);
  float u = ((float)s - dynB[b*4 + k]) / dynA[b*4 + k];
  psi[i] = 0.86732507f*(1.f - u*u)*expf(-0.5f*u*u);
}
__global__ __launch_bounds__(128) void k_final(const US* __restrict__ base, const US* __restrict__ kan,
    const US* __restrict__ gate, const void* __restrict__ x,
    void* __restrict__ out, const float* __restrict__ lng, const float* __restrict__ lnb,
    const int* __restrict__ fl){
  int isf = fl[0];
  long row = blockIdx.x;
  int t = threadIdx.x;
  long off = row*DD + t*4;
  ushort4 bs = *(const ushort4*)&base[off];
  ushort4 gt = *(const ushort4*)&gate[off];
  ushort4 kn = *(const ushort4*)&kan[off];
  float xv[4];
  if (isf){ float4 q = *(const float4*)((const float*)x + off); xv[0]=q.x; xv[1]=q.y; xv[2]=q.z; xv[3]=q.w; }
  else { ushort4 q = *(const ushort4*)((const US*)x + off); xv[0]=b2sf(q.x); xv[1]=b2sf(q.y); xv[2]=b2sf(q.z); xv[3]=b2sf(q.w); }
  float bv[4] = {b2sf(bs.x), b2sf(bs.y), b2sf(bs.z), b2sf(bs.w)};
  float gv[4] = {b2sf(gt.x), b2sf(gt.y), b2sf(gt.z), b2sf(gt.w)};
  const US* kp = (const US*)&kn;
  float y[4];
  float sm = 0.f, ssq = 0.f;
  #pragma unroll
  for (int r = 0; r < 4; r++){
    float amp = 2.f/(1.f + expf(-gv[r]));
    y[r] = bv[r] + b2sf(kp[r])*amp + xv[r];
    sm += y[r]; ssq += y[r]*y[r];
  }
  for (int o = 32; o; o >>= 1){ sm += __shfl_down(sm, o); ssq += __shfl_down(ssq, o); }
  __shared__ float sh[4];
  int lane = t & 63, wid = t >> 6;
  if (lane == 0){ sh[wid*2] = sm; sh[wid*2+1] = ssq; }
  __syncthreads();
  float S1 = sh[0] + sh[2], S2 = sh[1] + sh[3];
  float mean = S1*(1.f/DD), var = S2*(1.f/DD) - mean*mean;
  float rstd = rsqrtf(var + 1e-5f);
  #pragma unroll
  for (int r = 0; r < 4; r++){
    int d = t*4 + r;
    float val = (y[r] - mean)*rstd*lng[d] + lnb[d];
    if (isf) ((float*)out)[off + r] = val;
    else     ((US*)out)[off + r] = f2b(val);
  }
}

extern "C" void kernel_launch(void* const* d_in, const int* in_sizes, int n_in,
                              void* d_out, int out_size, void* d_ws, size_t ws_size,
                              hipStream_t stream){
  const void* x       = d_in[0];
  const void* conv_w  = d_in[1];
  const void* conv_b  = d_in[2];
  const void* fusion_w= d_in[3];
  const void* fusion_b= d_in[4];
  const void* refine_w= d_in[5];
  const void* refine_b= d_in[6];
  const void* hyp1_w  = d_in[7];
  const void* hyp1_b  = d_in[8];
  const void* bn_g    = d_in[9];
  const void* bn_b    = d_in[10];
  const void* hyp2_w  = d_in[11];
  const void* hyp2_b  = d_in[12];
  const void* proj_w  = d_in[13];
  const void* proj_b  = d_in[14];
  const void* gate_w  = d_in[15];
  const void* gate_b  = d_in[16];
  const void* base_w  = d_in[17];
  const void* base_b  = d_in[18];
  const void* wav_w   = d_in[19];
  const void* wav_b   = d_in[20];
  const void* ln_g    = d_in[21];
  const void* ln_b    = d_in[22];

  char* wsb = (char*)d_ws;
  long off = 0;
  auto AA = [&](long bytes)->char*{ char* p = wsb + off; off += (bytes + 255) & ~255L; return p; };
  US* smA   = (US*)AA((long)NB*SS*DD*2);
  US* smB   = (US*)AA((long)NB*SS*DD*2);
  US* xTh   = (US*)AA((long)NB*SS*DD*2);
  US* cc    = (US*)AA((long)NB*SS*2048*2);
  US* baseB = (US*)AA((long)NB*SS*DD*2);
  US* WBLK  = (US*)AA(7733248L*2);
  US* Cm    = (US*)AA(1024L*1024*2);
  float* gvec = (float*)AA(1024*4);
  float* FBLK = (float*)AA(11016L*4);
  float* feat = (float*)AA(16*256*4);
  float* part = (float*)AA(16*8*256*4);
  float* dynA = (float*)AA(64*4);
  float* dynB = (float*)AA(64*4);
  float* psi  = (float*)AA((long)NB*4*SS*4);
  int* flag   = (int*)AA(64);
  if ((size_t)off > ws_size) return;

  US* Wc  = WBLK;
  US* Wr  = Wc  + 3145728L;
  US* Wh1 = Wr  + 786432L;
  US* Wh2 = Wh1 + 786432L;
  US* Wwv = Wh2 + 393216L;
  US* Fw  = Wwv + 1048576L;
  US* BW  = Fw  + 1048576L;
  US* GW  = BW  + 262144L;
  float* cb_f = FBLK;
  float* fz_b = cb_f + 2048;
  float* rf_b = fz_b + 512;
  float* h1_b = rf_b + 512;
  float* h2_b = h1_b + 512;
  float* bs_b = h2_b + 256;
  float* gt_b = bs_b + 512;
  float* wv_b = gt_b + 512;
  float* bngf = wv_b + 2048;
  float* bnbf = bngf + 512;
  float* pwf  = bnbf + 512;
  float* pbf  = pwf  + 2048;
  float* lngf = pbf  + 8;
  float* lnbf = lngf + 512;
  US* spike = cc;
  US* baseO = cc + 8388608L;
  US* kanb  = cc + 16777216L;
  US* h2b   = cc + 25165824L;

  auto g1 = [](long n){ return dim3((unsigned)((n + 255)/256)); };
  const long sAct = (long)SS*DD*2;
  const long sCC  = (long)SS*2048*2;
  const long oAct = (long)SS*DD;
  const long oCC  = (long)SS*2048;
  const long oH2  = (long)SS*HD;

  k_detect<<<1, 256, 0, stream>>>(x, flag);

  { WTab wt;
    const void* srcs[8] = {conv_w, refine_w, hyp1_w, hyp2_w, wav_w, fusion_w, base_w, gate_w};
    long sizes[8] = {3145728, 786432, 786432, 393216, 1048576, 1048576, 262144, 262144};
    int types[8] = {0,0,0,0,1,2,2,2};
    int Cs[8]    = {512,512,512,512,0,0,0,0};
    long acc_ = 0;
    for (int i = 0; i < 8; i++){ wt.src[i]=srcs[i]; wt.start[i]=acc_; wt.type[i]=types[i]; wt.C[i]=Cs[i]; acc_ += sizes[i]; }
    wt.start[8] = acc_;
    k_prep_w<<<g1(acc_), 256, 0, stream>>>(wt, WBLK, flag);
  }
  { FTab ft;
    const void* srcs[14] = {conv_b, fusion_b, refine_b, hyp1_b, hyp2_b, base_b, gate_b,
                            wav_b, bn_g, bn_b, proj_w, proj_b, ln_g, ln_b};
    int sizes[14] = {2048,512,512,512,256,512,512,2048,512,512,2048,8,512,512};
    int acc_ = 0;
    for (int i = 0; i < 14; i++){ ft.src[i]=srcs[i]; ft.start[i]=acc_; acc_ += sizes[i]; }
    ft.start[14] = acc_;
    k_cvt_all<<<g1(acc_), 256, 0, stream>>>(ft, FBLK, flag);
  }
  k_build_g<<<g1(SS), 256, 0, stream>>>(gvec);
  k_build_cmat<<<g1((long)SS*SS), 256, 0, stream>>>(gvec, Cm);
  k_transpose_b<<<dim3(SS/32, DD/32, NB), 256, 0, stream>>>(x, xTh, flag);

  // circulant low-pass: smA[b][s][d]
  k_mfma<5,false><<<dim3(4*NB, 8), 256, 0, stream>>>(Cm, xTh, smA,
      4, 1024, (long)DD*SS*2, SS*2, 0, oAct, DD,
      nullptr, nullptr, nullptr, nullptr, nullptr, nullptr, nullptr, nullptr);

  // it 0: 1-barrier-per-slice 256^2 conv -> fusion
  k_mfma8<1,true><<<dim3(4*NB, 8), 512, 0, stream>>>(Wc, smA, cc,
      4, 1536, sAct, DD*2, -1, oCC, 2048, cb_f);
  k_mfma<0,false><<<dim3(8*NB, 4), 256, 0, stream>>>(Fw, cc, smB,
      8, 2048, sCC, 4096, 0, oAct, DD,
      fz_b, nullptr, nullptr, nullptr, nullptr, nullptr, nullptr, nullptr);
  // it 1: conv -> fusion (+fused diff & silu)
  k_mfma8<1,true><<<dim3(4*NB, 8), 512, 0, stream>>>(Wc, smB, cc,
      4, 1536, sAct, DD*2, -1, oCC, 2048, cb_f);
  k_mfma<6,false><<<dim3(8*NB, 4), 256, 0, stream>>>(Fw, cc, smA,
      8, 2048, sCC, 4096, 0, oAct, DD,
      fz_b, nullptr, nullptr, nullptr, x, smB, baseB, flag);

  // spike = refine(diff)
  k_mfma<0,true><<<dim3(8*NB, 4), 256, 0, stream>>>(Wr, smB, spike,
      8, 1536, sAct, DD*2, 1, oAct, DD,
      rf_b, nullptr, nullptr, nullptr, nullptr, nullptr, nullptr, nullptr);

  // hypernet
  k_mfma<2,true><<<dim3(8*NB, 4), 256, 0, stream>>>(Wh1, smA, xTh,
      8, 1536, sAct, DD*2, 1, oAct, DD,
      h1_b, bngf, bnbf, nullptr, nullptr, nullptr, nullptr, nullptr);
  k_mfma<3,true><<<dim3(8*NB, 2), 256, 0, stream>>>(Wh2, xTh, h2b,
      8, 1536, sAct, DD*2, 1, oH2, HD,
      h2_b, nullptr, nullptr, nullptr, nullptr, nullptr, nullptr, nullptr);
  k_pool1<<<NB*8, 256, 0, stream>>>(h2b, part);
  k_pool2<<<NB, 256, 0, stream>>>(part, feat);
  k_params<<<1, 128, 0, stream>>>(feat, pwf, pbf, dynA, dynB);
  k_psi<<<g1(NB*4*SS), 256, 0, stream>>>(dynA, dynB, psi);

  // base / gate
  k_mfma<0,false><<<dim3(8*NB, 4), 256, 0, stream>>>(BW, baseB, baseO,
      8, 512, sAct, DD*2, 0, oAct, DD,
      bs_b, nullptr, nullptr, nullptr, nullptr, nullptr, nullptr, nullptr);
  k_mfma<0,false><<<dim3(8*NB, 4), 256, 0, stream>>>(GW, baseO, xTh,
      8, 512, sAct, DD*2, 0, oAct, DD,
      gt_b, nullptr, nullptr, nullptr, nullptr, nullptr, nullptr, nullptr);

  // psi-fused wavelet
  k_mfma<4,false><<<dim3(8*NB, 4), 256, 0, stream>>>(Wwv, spike, kanb,
      8, 512, sAct, DD*2, 0, oAct, DD,
      wv_b, nullptr, nullptr, psi, nullptr, nullptr, nullptr, nullptr);

  // combine + residual + LayerNorm
  k_final<<<NB*SS, 128, 0, stream>>>(baseO, kanb, xTh, x, d_out, lngf, lnbf, flag);
}